// Round 7
// baseline (619.345 us; speedup 1.0000x reference)
//
#include <hip/hip_runtime.h>

#define NEDGES 1600000
#define NNODES 100000
#define NF 128
#define NSCAN_BLK 98     // ceil(100000/1024)
#define GATHER_REP 3     // instrumentation: repeat gather to top rocprof table

typedef short s16x8 __attribute__((ext_vector_type(8)));
typedef float f32x4 __attribute__((ext_vector_type(4)));

// ---- workspace byte layout ----
#define CNT_B    0u         // int[100000]
#define ROWPTR_B 400000u    // int[100001]
#define CURSOR_B 800016u    // int[100000]
#define EIDS_B   1200016u   // uint[1600000]  packed (eid<<4)|(dst&15)
#define WBF_B    7600016u   // ushort[16384]
#define BSUM_B   7632784u   // int[98]
#define AGG_B    7633184u   // unsigned[100000*64]  bf16-packed agg rows, 25.6MB

static __device__ __forceinline__ unsigned short f2bf(float x) {
    unsigned u = __float_as_uint(x);
    return (unsigned short)((u + 0x7fffu + ((u >> 16) & 1u)) >> 16);  // RNE
}

// hist + W->bf16 conversion folded together (saves a dispatch).
__global__ __launch_bounds__(256) void k_hist(const int* __restrict__ dst,
                                              int* __restrict__ cnt,
                                              const float* __restrict__ W,
                                              unsigned short* __restrict__ Wb) {
    int i = blockIdx.x * 256 + threadIdx.x;
    if (i < NF * NF) Wb[i] = f2bf(W[i]);
    if (i < NEDGES) atomicAdd(&cnt[dst[i]], 1);
}

__global__ __launch_bounds__(1024) void k_scan1(const int* __restrict__ cnt,
                                                int* __restrict__ rowptr,
                                                int* __restrict__ bsum) {
    const int t = threadIdx.x;
    const int i = blockIdx.x * 1024 + t;
    const int v = (i < NNODES) ? cnt[i] : 0;
    __shared__ int ps[1024];
    ps[t] = v;
    __syncthreads();
    for (int off = 1; off < 1024; off <<= 1) {
        int u = (t >= off) ? ps[t - off] : 0;
        __syncthreads();
        ps[t] += u;
        __syncthreads();
    }
    if (i < NNODES) rowptr[i] = ps[t] - v;
    if (t == 1023) bsum[blockIdx.x] = ps[1023];
}

// scan2+scan3 merged: each block reduces bsum[0..blockIdx.x) itself.
__global__ __launch_bounds__(1024) void k_scan23(int* __restrict__ rowptr,
                                                 const int* __restrict__ bsum,
                                                 int* __restrict__ cursor) {
    const int t = threadIdx.x;
    const int i = blockIdx.x * 1024 + t;
    __shared__ int red[1024];
    red[t] = (t < blockIdx.x) ? bsum[t] : 0;   // blockIdx.x <= 97
    __syncthreads();
    for (int s = 512; s > 0; s >>= 1) {
        if (t < s) red[t] += red[t + s];
        __syncthreads();
    }
    const int off = red[0];
    if (i < NNODES) {
        const int r = rowptr[i] + off;
        rowptr[i] = r;
        cursor[i] = r;
    }
    if (blockIdx.x == 0 && t == 0) rowptr[NNODES] = NEDGES;
}

__global__ __launch_bounds__(256) void k_fill(const int* __restrict__ dst,
                                              int* __restrict__ cursor,
                                              unsigned* __restrict__ eids) {
    int i = blockIdx.x * 256 + threadIdx.x;
    if (i < NEDGES) {
        const int d = dst[i];
        const int p = atomicAdd(&cursor[d], 1);
        eids[p] = ((unsigned)i << 4) | (unsigned)(d & 15);
    }
}

// ---------------------------------------------------------------------------
// Gather + mean -> bf16 agg rows in GLOBAL ws (split from MM for rocprof
// attribution). Structure = R4/R6 validated gather: per-wave contiguous
// chunks, coalesced eids lane-load + readlane broadcast, 16-deep batches of
// independent 512B loads, segmented REGISTER accumulation, conflict-free LDS
// flush. GATHER_REP repeats the whole pass (idempotent) so this dispatch
// exceeds the harness's 481us poison-fills and shows up in rocprof top-5.
// ---------------------------------------------------------------------------
__global__ __launch_bounds__(256) void k_gather(
        const float* __restrict__ edge, const int* __restrict__ rowptr,
        const unsigned* __restrict__ eids, unsigned* __restrict__ agg) {
    __shared__ float aggf[16][132];
    const int tid  = threadIdx.x;
    const int lane = tid & 63;
    const int wv   = tid >> 6;
    const int n0   = blockIdx.x * 16;

    const int eb    = rowptr[n0];
    const int ee    = rowptr[n0 + 16];
    const int chunk = (ee - eb + 3) >> 2;
    const int wcs   = eb + wv * chunk;
    const int wce   = min(wcs + chunk, ee);

    for (int rep = 0; rep < GATHER_REP; ++rep) {
        for (int idx = tid; idx < 16 * 132; idx += 256)
            (&aggf[0][0])[idx] = 0.0f;
        __syncthreads();

        int   cur = -1;
        float a0 = 0.f, a1 = 0.f;

        for (int base = wcs; base < wce; base += 64) {
            const int m = min(64, wce - base);
            const unsigned ev = (lane < m) ? eids[base + lane] : 0u;
            int b = 0;
            for (; b + 16 <= m; b += 16) {
                unsigned id[16];
                int      rw[16];
                #pragma unroll
                for (int j = 0; j < 16; ++j) {
                    const unsigned u = (unsigned)__builtin_amdgcn_readlane((int)ev, b + j);
                    id[j] = u >> 4;
                    rw[j] = (int)(u & 15u);
                }
                float2 xv[16];
                #pragma unroll
                for (int j = 0; j < 16; ++j)
                    xv[j] = *(const float2*)(edge + (size_t)id[j] * NF + lane * 2);
                #pragma unroll
                for (int j = 0; j < 16; ++j) {
                    if (rw[j] != cur) {            // wave-uniform scalar branch
                        if (cur >= 0) {
                            atomicAdd(&aggf[cur][lane], a0);
                            atomicAdd(&aggf[cur][64 + lane], a1);
                        }
                        cur = rw[j];
                        a0 = 0.f; a1 = 0.f;
                    }
                    a0 += xv[j].x;
                    a1 += xv[j].y;
                }
            }
            for (; b < m; ++b) {
                const unsigned u = (unsigned)__builtin_amdgcn_readlane((int)ev, b);
                const float2 v = *(const float2*)(edge + (size_t)(u >> 4) * NF + lane * 2);
                const int r = (int)(u & 15u);
                if (r != cur) {
                    if (cur >= 0) {
                        atomicAdd(&aggf[cur][lane], a0);
                        atomicAdd(&aggf[cur][64 + lane], a1);
                    }
                    cur = r;
                    a0 = 0.f; a1 = 0.f;
                }
                a0 += v.x;
                a1 += v.y;
            }
        }
        if (cur >= 0) {
            atomicAdd(&aggf[cur][lane], a0);
            atomicAdd(&aggf[cur][64 + lane], a1);
        }
        __syncthreads();

        // mean + bf16 pack -> global agg row (uint4 = 16 threads x 16B / row).
        {
            const int r  = tid >> 4;
            const int p0 = (tid & 15) * 4;
            const int cs = rowptr[n0 + r];
            const int ce = rowptr[n0 + r + 1];
            const float inv = 1.0f / fmaxf((float)(ce - cs), 1.0f);
            const float4 xv = *(const float4*)&aggf[r][p0];
            const float4 yv = *(const float4*)&aggf[r][64 + p0];
            const float xa[4] = {xv.x, xv.y, xv.z, xv.w};
            const float ya[4] = {yv.x, yv.y, yv.z, yv.w};
            uint4 pk;
            pk.x = (unsigned)f2bf(xa[0] * inv) | ((unsigned)f2bf(ya[0] * inv) << 16);
            pk.y = (unsigned)f2bf(xa[1] * inv) | ((unsigned)f2bf(ya[1] * inv) << 16);
            pk.z = (unsigned)f2bf(xa[2] * inv) | ((unsigned)f2bf(ya[2] * inv) << 16);
            pk.w = (unsigned)f2bf(xa[3] * inv) | ((unsigned)f2bf(ya[3] * inv) << 16);
            *(uint4*)(agg + (size_t)(n0 + r) * 64 + p0) = pk;
        }
        __syncthreads();
    }
}

// ---------------------------------------------------------------------------
// MM: out = relu(W @ agg + b). One block = 16 nodes. Cooperative coalesced
// load of 16 agg rows into XOR-swizzled LDS, then the verified R6 phase-3
// MFMA (D layout: col=lane&15, row=(lane>>4)*4+reg).
// ---------------------------------------------------------------------------
__global__ __launch_bounds__(256) void k_mm(
        const unsigned* __restrict__ agg, const unsigned short* __restrict__ Wb,
        const float* __restrict__ bias, float* __restrict__ out) {
    __shared__ __align__(16) char aggb[16 * 256];
    const int tid  = threadIdx.x;
    const int lane = tid & 63;
    const int wv   = tid >> 6;
    const int l15  = lane & 15;
    const int l4   = lane >> 4;
    const int n0   = blockIdx.x * 16;

    // thread t loads words 4t..4t+3 (uint4) = row t>>4, bytes (t&15)*16..+16
    {
        const uint4 v = *(const uint4*)(agg + (size_t)n0 * 64 + tid * 4);
        const int r  = tid >> 4;
        const int wb = (tid & 15) * 16;
        *(uint4*)(aggb + ((r * 256 + wb) ^ ((r & 7) << 4))) = v;
    }
    __syncthreads();

    #pragma unroll
    for (int t = 0; t < 2; ++t) {
        const int j0 = (wv * 2 + t) * 16;
        f32x4 acc = {0.f, 0.f, 0.f, 0.f};
        #pragma unroll
        for (int ks = 0; ks < 4; ++ks) {
            const s16x8 wfv = *(const s16x8*)((const char*)Wb +
                                              (j0 + l15) * 256 + ks * 64 + l4 * 16);
            const int byt = ((l15 * 256 + ks * 64 + l4 * 16) ^ ((l15 & 7) << 4));
            const s16x8 av = *(const s16x8*)(aggb + byt);
            acc = __builtin_amdgcn_mfma_f32_16x16x32_bf16(av, wfv, acc, 0, 0, 0);
        }
        const float bj = bias[j0 + l15];
        #pragma unroll
        for (int r = 0; r < 4; ++r) {
            const int m = l4 * 4 + r;
            out[(size_t)(n0 + m) * NF + j0 + l15] = fmaxf(acc[r] + bj, 0.f);
        }
    }
}

extern "C" void kernel_launch(void* const* d_in, const int* in_sizes, int n_in,
                              void* d_out, int out_size, void* d_ws, size_t ws_size,
                              hipStream_t stream) {
    const float* edge = (const float*)d_in[0];
    const int*   dst  = (const int*)d_in[1];
    const float* W    = (const float*)d_in[2];
    const float* b    = (const float*)d_in[3];
    float* out = (float*)d_out;

    char* ws = (char*)d_ws;
    int*            cnt    = (int*)(ws + CNT_B);
    int*            rowptr = (int*)(ws + ROWPTR_B);
    int*            cursor = (int*)(ws + CURSOR_B);
    unsigned*       eids   = (unsigned*)(ws + EIDS_B);
    unsigned short* Wb     = (unsigned short*)(ws + WBF_B);
    int*            bsum   = (int*)(ws + BSUM_B);
    unsigned*       agg    = (unsigned*)(ws + AGG_B);

    hipMemsetAsync(cnt, 0, (size_t)NNODES * sizeof(int), stream);

    k_hist<<<(NEDGES + 255) / 256, 256, 0, stream>>>(dst, cnt, W, Wb);
    k_scan1<<<NSCAN_BLK, 1024, 0, stream>>>(cnt, rowptr, bsum);
    k_scan23<<<NSCAN_BLK, 1024, 0, stream>>>(rowptr, bsum, cursor);
    k_fill<<<(NEDGES + 255) / 256, 256, 0, stream>>>(dst, cursor, eids);
    k_gather<<<NNODES / 16, 256, 0, stream>>>(edge, rowptr, eids, agg);
    k_mm<<<NNODES / 16, 256, 0, stream>>>(agg, Wb, b, out);
}